// Round 1
// baseline (454.744 us; speedup 1.0000x reference)
//
#include <hip/hip_runtime.h>

#define IN_F 8192
#define OUT_F 8192
#define BATCH 64
#define GROUPSIZE 128

// ---------------------------------------------------------------------------
// Kernel 1: out[r][c] = bias[c]   (output must be initialized every call —
// harness poisons d_out once and k-split GEMM accumulates atomically)
// ---------------------------------------------------------------------------
__global__ void wol_init_out(const float* __restrict__ bias,
                             float* __restrict__ out) {
    int idx = blockIdx.x * 256 + threadIdx.x;
    if (idx < BATCH * OUT_F) {
        out[idx] = bias[idx & (OUT_F - 1)];
    }
}

// ---------------------------------------------------------------------------
// Kernel 2: dequant + GEMM, K-split with fp32 atomicAdd.
// Grid = 32 column-tiles (256 cols each) x 16 K-splits = 512 blocks.
// Thread t owns out column ct*256+t; holds 64 fp32 accumulators (one per
// batch row); walks its K-range of 512 input channels (4 quant groups).
// x addresses are wave-uniform (only depend on r,i) -> scalar-cache
// broadcast loads; qweight reads are lane-consecutive -> fully coalesced,
// each packed word read exactly once chip-wide.
// ---------------------------------------------------------------------------
__global__ void __launch_bounds__(256)
wol_gemm_dq(const float* __restrict__ x,
            const int*   __restrict__ qw,
            const int*   __restrict__ qz,
            const float* __restrict__ sc,
            float*       __restrict__ out) {
    const int ct = blockIdx.x & 31;   // column tile
    const int ks = blockIdx.x >> 5;   // K split 0..15
    const int col = ct * 256 + (int)threadIdx.x;
    const int ibase = ks * 512;       // this block's K range start

    float acc[BATCH];
#pragma unroll
    for (int r = 0; r < BATCH; ++r) acc[r] = 0.0f;

    for (int g4 = 0; g4 < 4; ++g4) {          // 4 quant groups of 128
        const int g = (ibase >> 7) + g4;
        const float scale = sc[g * OUT_F + col];
        const unsigned qzw = (unsigned)qz[g * (OUT_F / 8) + (col >> 3)];
        // optimum format stores zp-1; recover with wraparound: zp=(nib+1)&15
        const int zp = (int)(((qzw >> ((col & 7) * 4)) + 1u) & 15u);
        const float zs = (float)zp * scale;   // w = nib*scale - zs
        const int i0 = ibase + g4 * GROUPSIZE;

        for (int w8 = 0; w8 < 16; ++w8) {     // 16 packed words per group
            const int i = i0 + w8 * 8;
            const unsigned q = (unsigned)qw[(i >> 3) * OUT_F + col];
            float wv[8];
#pragma unroll
            for (int j = 0; j < 8; ++j) {
                // low nibble = first (lowest) input channel
                wv[j] = (float)((q >> (4 * j)) & 15u) * scale - zs;
            }
#pragma unroll
            for (int r = 0; r < BATCH; ++r) {
                const float4 x0 = *(const float4*)&x[r * IN_F + i];
                const float4 x1 = *(const float4*)&x[r * IN_F + i + 4];
                acc[r] += x0.x * wv[0] + x0.y * wv[1] + x0.z * wv[2] +
                          x0.w * wv[3] + x1.x * wv[4] + x1.y * wv[5] +
                          x1.z * wv[6] + x1.w * wv[7];
            }
        }
    }

#pragma unroll
    for (int r = 0; r < BATCH; ++r) {
        atomicAdd(&out[r * OUT_F + col], acc[r]);
    }
}

extern "C" void kernel_launch(void* const* d_in, const int* in_sizes, int n_in,
                              void* d_out, int out_size, void* d_ws, size_t ws_size,
                              hipStream_t stream) {
    const float* x    = (const float*)d_in[0];
    const int*   qw   = (const int*)d_in[1];
    const int*   qz   = (const int*)d_in[2];
    const float* sc   = (const float*)d_in[3];
    const float* bias = (const float*)d_in[4];
    float* out = (float*)d_out;

    (void)in_sizes; (void)n_in; (void)d_ws; (void)ws_size; (void)out_size;

    wol_init_out<<<(BATCH * OUT_F + 255) / 256, 256, 0, stream>>>(bias, out);
    wol_gemm_dq<<<512, 256, 0, stream>>>(x, qw, qz, sc, out);
}

// Round 2
// 45.492 us; speedup vs baseline: 9.9961x; 9.9961x over previous
//
#include <hip/hip_runtime.h>
#include <hip/hip_bf16.h>

#define IN_F 8192
#define OUT_F 8192
#define BATCH 64

typedef __attribute__((ext_vector_type(8))) short bf16x8_t;  // 8 bf16 (4 VGPRs)
typedef __attribute__((ext_vector_type(4))) float f32x4_t;   // MFMA accumulator

// ---------------------------------------------------------------------------
// out[r][c] = bias[c]  (K-split GEMM accumulates on top via atomics)
// ---------------------------------------------------------------------------
__global__ void wol_init_out(const float* __restrict__ bias,
                             float* __restrict__ out) {
    int idx = blockIdx.x * 256 + threadIdx.x;
    if (idx < BATCH * OUT_F) out[idx] = bias[idx & (OUT_F - 1)];
}

// ---------------------------------------------------------------------------
// x fp32 [64][8192] -> xb bf16, fragment-major: xb[(k8*64 + row)*8 + j]
// (k8 = k/8). A-fragment load in GEMM is then 16B/lane, 256B-contiguous
// per 16-lane group.
// ---------------------------------------------------------------------------
__global__ void wol_xconv(const float* __restrict__ x,
                          ushort* __restrict__ xb) {
    int g = blockIdx.x * 256 + threadIdx.x;   // 65536 threads
    int k8  = g & 1023;                       // wave: consecutive k8 -> coalesced reads
    int row = g >> 10;
    const float4* src = (const float4*)&x[row * IN_F + k8 * 8];
    float4 a = src[0], b = src[1];
    float f[8] = {a.x, a.y, a.z, a.w, b.x, b.y, b.z, b.w};
    union { ushort u[8]; bf16x8_t v; } o;
#pragma unroll
    for (int j = 0; j < 8; ++j) {
        __hip_bfloat16 hb = __float2bfloat16(f[j]);
        o.u[j] = *reinterpret_cast<ushort*>(&hb);
    }
    *(bf16x8_t*)&xb[((size_t)k8 * 64 + row) * 8] = o.v;
}

// ---------------------------------------------------------------------------
// MFMA GEMM with in-register dequant.
// Grid: 32 N-tiles (256 cols) x 8 K-splits = 256 blocks, 512 threads.
// Wave w: nq = w&3 (64-col quarter), kh = w>>2 (512-K half). Wave tile 64x64:
// 4 M-frags x 4 N-frags of mfma_f32_16x16x32_bf16. One qweight int32 per
// lane = one B-fragment K-slice (8 contiguous nibbles). kh pairs reduce via
// LDS, then fp32 atomicAdd into bias-initialized out.
// ---------------------------------------------------------------------------
__global__ void __launch_bounds__(512)
wol_mfma(const int*   __restrict__ qw,
         const int*   __restrict__ qz,
         const float* __restrict__ sc,
         const ushort* __restrict__ xb,
         float*       __restrict__ out) {
    const int nt   = blockIdx.x & 31;
    const int ks   = blockIdx.x >> 5;
    const int wid  = threadIdx.x >> 6;
    const int lane = threadIdx.x & 63;
    const int nq   = wid & 3;
    const int kh   = wid >> 2;
    const int ln   = lane & 15;
    const int kb   = lane >> 4;               // k-subblock 0..3
    const int colbase = nt * 256 + nq * 64;
    const int kwave   = ks * 1024 + kh * 512; // this wave's K range (512 = 4 groups)
    const int gbase   = kwave >> 7;

    f32x4_t acc[4][4];
#pragma unroll
    for (int mi = 0; mi < 4; ++mi)
#pragma unroll
        for (int nj = 0; nj < 4; ++nj) acc[mi][nj] = (f32x4_t)0.0f;

    for (int g = 0; g < 4; ++g) {             // 4 quant groups of 128 K
        const int gg = gbase + g;
        float s[4], dz[4];
#pragma unroll
        for (int nj = 0; nj < 4; ++nj) {
            const int c = colbase + nj * 16 + ln;
            const float sv = sc[gg * OUT_F + c];
            const unsigned z = (unsigned)qz[gg * (OUT_F / 8) + (c >> 3)];
            const unsigned zp = ((z >> ((c & 7) * 4)) + 1u) & 15u;  // stored zp-1, wrap
            s[nj] = sv;
            dz[nj] = -(float)zp * sv;          // w = nib*s + dz
        }
        const int k0 = kwave + g * 128;
#pragma unroll
        for (int kt = 0; kt < 4; ++kt) {      // 4 K-steps of 32
            const int kk = k0 + kt * 32;
            const int qrow = (kk >> 3) + kb;  // packed-word row for this lane
            unsigned q[4];
#pragma unroll
            for (int nj = 0; nj < 4; ++nj)
                q[nj] = (unsigned)qw[(size_t)qrow * OUT_F + colbase + nj * 16 + ln];
            bf16x8_t af[4];
#pragma unroll
            for (int mi = 0; mi < 4; ++mi)
                af[mi] = *(const bf16x8_t*)&xb[(size_t)qrow * 512 + (mi * 16 + ln) * 8];
#pragma unroll
            for (int nj = 0; nj < 4; ++nj) {
                union { ushort u[8]; bf16x8_t v; } bu;
#pragma unroll
                for (int j = 0; j < 8; ++j) {
                    const float wf = (float)((q[nj] >> (4 * j)) & 15u) * s[nj] + dz[nj];
                    __hip_bfloat16 hb = __float2bfloat16(wf);
                    bu.u[j] = *reinterpret_cast<ushort*>(&hb);
                }
#pragma unroll
                for (int mi = 0; mi < 4; ++mi)
                    acc[mi][nj] = __builtin_amdgcn_mfma_f32_16x16x32_bf16(
                        af[mi], bu.v, acc[mi][nj], 0, 0, 0);
            }
        }
    }

    // ---- in-block reduction of the two K-halves, then atomic epilogue ----
    __shared__ f32x4_t red[4][16][64];        // 64 KiB
    if (kh == 1) {
#pragma unroll
        for (int mi = 0; mi < 4; ++mi)
#pragma unroll
            for (int nj = 0; nj < 4; ++nj)
                red[nq][mi * 4 + nj][lane] = acc[mi][nj];
    }
    __syncthreads();
    if (kh == 0) {
#pragma unroll
        for (int mi = 0; mi < 4; ++mi)
#pragma unroll
            for (int nj = 0; nj < 4; ++nj) {
                f32x4_t v = acc[mi][nj];
                const f32x4_t r = red[nq][mi * 4 + nj][lane];
#pragma unroll
                for (int j = 0; j < 4; ++j) {
                    const int row = mi * 16 + (lane >> 4) * 4 + j;   // C/D layout (m89)
                    const int col = colbase + nj * 16 + ln;
                    atomicAdd(&out[(size_t)row * OUT_F + col], v[j] + r[j]);
                }
            }
    }
}

extern "C" void kernel_launch(void* const* d_in, const int* in_sizes, int n_in,
                              void* d_out, int out_size, void* d_ws, size_t ws_size,
                              hipStream_t stream) {
    const float* x    = (const float*)d_in[0];
    const int*   qw   = (const int*)d_in[1];
    const int*   qz   = (const int*)d_in[2];
    const float* sc   = (const float*)d_in[3];
    const float* bias = (const float*)d_in[4];
    float*  out = (float*)d_out;
    ushort* xb  = (ushort*)d_ws;              // 1 MiB bf16 activations

    (void)in_sizes; (void)n_in; (void)ws_size; (void)out_size;

    wol_init_out<<<(BATCH * OUT_F + 255) / 256, 256, 0, stream>>>(bias, out);
    wol_xconv<<<256, 256, 0, stream>>>(x, xb);
    wol_mfma<<<256, 512, 0, stream>>>(qw, qz, sc, xb, out);
}